// Round 1
// baseline (654.693 us; speedup 1.0000x reference)
//
#include <hip/hip_runtime.h>
#include <hip/hip_bf16.h>
#include <cstdint>

typedef __attribute__((ext_vector_type(4))) float f32x4;
typedef __attribute__((ext_vector_type(8))) short bf16x8;

__device__ inline unsigned short f2bf(float f) {
    union { float f; unsigned u; } v; v.f = f;
    unsigned r = v.u + 0x7FFFu + ((v.u >> 16) & 1u);
    return (unsigned short)(r >> 16);
}
__device__ inline float bf2f(unsigned short h) {
    union { unsigned u; float f; } v; v.u = ((unsigned)h) << 16;
    return v.f;
}

// ---------------------------------------------------------------- prep
__global__ void prep_kernel(
    const float* __restrict__ We,
    const float* __restrict__ Wul, const float* __restrict__ Wau, const float* __restrict__ WVu,
    const float* __restrict__ Wvl, const float* __restrict__ Wav, const float* __restrict__ WVv,
    const float* __restrict__ Wwu, const float* __restrict__ Wwv,
    const float* __restrict__ bul, const float* __restrict__ bau, const float* __restrict__ bVu,
    const float* __restrict__ bvl, const float* __restrict__ bav, const float* __restrict__ bVv,
    unsigned short* __restrict__ WeT, unsigned short* __restrict__ WuT, unsigned short* __restrict__ WvT,
    unsigned short* __restrict__ WwuT, unsigned short* __restrict__ WwvT,
    float* __restrict__ bcu, float* __restrict__ bcv)
{
    int tid0 = blockIdx.x * blockDim.x + threadIdx.x;
    int stride = gridDim.x * blockDim.x;
    for (int i = tid0; i < 64 * 64; i += stride) { int c = i >> 6, k = i & 63; WeT[i] = f2bf(We[k * 64 + c]); }
    for (int i = tid0; i < 224 * 64; i += stride) {
        int c = i >> 6, k = i & 63;
        float v = (c < 64) ? Wul[k * 64 + c] : (c < 192) ? Wau[k * 128 + (c - 64)] : WVu[k * 32 + (c - 192)];
        WuT[i] = f2bf(v);
    }
    for (int i = tid0; i < 224 * 64; i += stride) {
        int c = i >> 6, k = i & 63;
        float v = (c < 64) ? Wvl[k * 64 + c] : (c < 192) ? Wav[k * 128 + (c - 64)] : WVv[k * 32 + (c - 192)];
        WvT[i] = f2bf(v);
    }
    for (int i = tid0; i < 32 * 128; i += stride) { int c = i >> 7, k = i & 127; WwuT[i] = f2bf(Wwu[k * 32 + c]); }
    for (int i = tid0; i < 32 * 128; i += stride) { int c = i >> 7, k = i & 127; WwvT[i] = f2bf(Wwv[k * 32 + c]); }
    for (int i = tid0; i < 224; i += stride) {
        bcu[i] = (i < 64) ? bul[i] : (i < 192) ? bau[i - 64] : bVu[i - 192];
        bcv[i] = (i < 64) ? bvl[i] : (i < 192) ? bav[i - 64] : bVv[i - 192];
    }
}

// ---------------------------------------------------------------- node pre:
// [64 nodes/block] feat@[Wl|Wa|WV] (K=64, N=224) -> he(bf16), att(bf16), outV(f32);
// also zero agg/sum for this node range.
__global__ __launch_bounds__(256) void node_pre_kernel(
    const float* __restrict__ feat, int N,
    const unsigned short* __restrict__ WT,   // [224][64] bf16 (c-major)
    const float* __restrict__ bcat,          // [224]
    unsigned short* __restrict__ he,         // [N][64]  bf16
    unsigned short* __restrict__ att,        // [N][128] bf16
    float* __restrict__ outV,                // out rows stride 64, cols 0..31
    float* __restrict__ agg,                 // [N][128] f32 (zeroed here)
    float* __restrict__ sums)                // [N] (zeroed here)
{
    __shared__ unsigned short lA[64 * 64];
    __shared__ unsigned short lW[224 * 64];
    int tid = threadIdx.x;
    int n0 = blockIdx.x * 64;

    const uint4* wsrc = (const uint4*)WT;
    for (int i = tid; i < 224 * 8; i += 256) {
        int r = i >> 3, ch = i & 7;
        *(uint4*)&lW[r * 64 + ((ch ^ (r & 7)) << 3)] = wsrc[i];
    }
    #pragma unroll
    for (int j = 0; j < 4; ++j) {
        int fi = j * 1024 + tid * 4;
        int r = fi >> 6, k = fi & 63;
        int n = n0 + r;
        float4 v = make_float4(0.f, 0.f, 0.f, 0.f);
        if (n < N) v = *(const float4*)&feat[(size_t)n * 64 + k];
        uint2 pk;
        pk.x = (unsigned)f2bf(v.x) | ((unsigned)f2bf(v.y) << 16);
        pk.y = (unsigned)f2bf(v.z) | ((unsigned)f2bf(v.w) << 16);
        *(uint2*)&lA[r * 64 + (((k >> 3) ^ (r & 7)) << 3) + (k & 7)] = pk;
    }
    {   // zero agg + sums
        float4 z = make_float4(0.f, 0.f, 0.f, 0.f);
        for (int i = tid; i < 64 * 32; i += 256) {
            int r = i >> 5, q = i & 31;
            int n = n0 + r;
            if (n < N) *(float4*)&agg[(size_t)n * 128 + q * 4] = z;
        }
        if (tid < 64) { int n = n0 + tid; if (n < N) sums[n] = 0.f; }
    }
    __syncthreads();

    int wv = tid >> 6, lane = tid & 63;
    int r0 = wv * 16;
    int lrow = lane & 15, lkg = lane >> 4;
    int rr = r0 + lrow;

    bf16x8 a[2];
    #pragma unroll
    for (int h = 0; h < 2; ++h) {
        int ch = h * 4 + lkg;
        a[h] = *(const bf16x8*)&lA[rr * 64 + ((ch ^ (rr & 7)) << 3)];
    }
    f32x4 acc[14];
    #pragma unroll
    for (int t = 0; t < 14; ++t) acc[t] = (f32x4){0.f, 0.f, 0.f, 0.f};
    #pragma unroll
    for (int t = 0; t < 14; ++t) {
        int row = t * 16 + lrow;
        #pragma unroll
        for (int h = 0; h < 2; ++h) {
            int ch = h * 4 + lkg;
            bf16x8 b = *(const bf16x8*)&lW[row * 64 + ((ch ^ (row & 7)) << 3)];
            acc[t] = __builtin_amdgcn_mfma_f32_16x16x32_bf16(a[h], b, acc[t], 0, 0, 0);
        }
    }
    #pragma unroll
    for (int t = 0; t < 14; ++t) {
        #pragma unroll
        for (int q = 0; q < 4; ++q) {
            int n = n0 + r0 + lkg * 4 + q;
            if (n >= N) continue;
            int c = t * 16 + lrow;
            float v = acc[t][q] + bcat[c];
            if (t < 4)       he[(size_t)n * 64 + c] = f2bf(v);
            else if (t < 12) att[(size_t)n * 128 + (c - 64)] = f2bf(v);
            else             outV[(size_t)n * 64 + (c - 192)] = v;
        }
    }
}

// ---------------------------------------------------------------- edge:
// [64 edges/block] out_he = e@We + be + he_src[src] + he_dst[dst];
// s = <[src_feat[src]|e], att_dst[dst]>; w = exp(s);
// atomic: sum[dst]+=w; agg[dst] += w*[src_feat[src]|e]
__global__ __launch_bounds__(256) void edge_kernel(
    const float* __restrict__ efeat, int E,
    const int* __restrict__ src, const int* __restrict__ dst,
    const float* __restrict__ src_feat,
    const unsigned short* __restrict__ he_src, const unsigned short* __restrict__ he_dst,
    const unsigned short* __restrict__ att_dst,
    const unsigned short* __restrict__ WeT,
    const float* __restrict__ be,
    float* __restrict__ out_he,
    float* __restrict__ agg, float* __restrict__ sums)
{
    __shared__ unsigned short lA[64 * 64];
    __shared__ unsigned short lW[64 * 64];
    int tid = threadIdx.x;
    int e0 = blockIdx.x * 64;

    const uint4* wsrc = (const uint4*)WeT;
    for (int i = tid; i < 512; i += 256) {
        int r = i >> 3, ch = i & 7;
        *(uint4*)&lW[r * 64 + ((ch ^ (r & 7)) << 3)] = wsrc[i];
    }
    #pragma unroll
    for (int j = 0; j < 4; ++j) {
        int fi = j * 1024 + tid * 4;
        int r = fi >> 6, k = fi & 63;
        int e = e0 + r;
        float4 v = make_float4(0.f, 0.f, 0.f, 0.f);
        if (e < E) v = *(const float4*)&efeat[(size_t)e * 64 + k];
        uint2 pk;
        pk.x = (unsigned)f2bf(v.x) | ((unsigned)f2bf(v.y) << 16);
        pk.y = (unsigned)f2bf(v.z) | ((unsigned)f2bf(v.w) << 16);
        *(uint2*)&lA[r * 64 + (((k >> 3) ^ (r & 7)) << 3) + (k & 7)] = pk;
    }
    __syncthreads();

    int wv = tid >> 6, lane = tid & 63;
    int r0 = wv * 16;
    int lrow = lane & 15, lkg = lane >> 4;
    int rr = r0 + lrow;

    bf16x8 a[2];
    #pragma unroll
    for (int h = 0; h < 2; ++h) {
        int ch = h * 4 + lkg;
        a[h] = *(const bf16x8*)&lA[rr * 64 + ((ch ^ (rr & 7)) << 3)];
    }
    f32x4 acc[4];
    #pragma unroll
    for (int t = 0; t < 4; ++t) acc[t] = (f32x4){0.f, 0.f, 0.f, 0.f};
    #pragma unroll
    for (int t = 0; t < 4; ++t) {
        int row = t * 16 + lrow;
        #pragma unroll
        for (int h = 0; h < 2; ++h) {
            int ch = h * 4 + lkg;
            bf16x8 b = *(const bf16x8*)&lW[row * 64 + ((ch ^ (row & 7)) << 3)];
            acc[t] = __builtin_amdgcn_mfma_f32_16x16x32_bf16(a[h], b, acc[t], 0, 0, 0);
        }
    }
    // epilogue: hf = acc + be + he_src[src] + he_dst[dst]
    #pragma unroll
    for (int q = 0; q < 4; ++q) {
        int e = e0 + r0 + lkg * 4 + q;
        if (e >= E) continue;
        int si = src[e], di = dst[e];
        #pragma unroll
        for (int t = 0; t < 4; ++t) {
            int c = t * 16 + lrow;
            float v = acc[t][q] + be[c]
                    + bf2f(he_src[(size_t)si * 64 + c])
                    + bf2f(he_dst[(size_t)di * 64 + c]);
            out_he[(size_t)e * 64 + c] = v;
        }
    }
    // score + aggregation phase (this wave's 16 edges)
    for (int q2 = 0; q2 < 16; ++q2) {
        int e = e0 + wv * 16 + q2;
        if (e >= E) continue;
        int si = src[e], di = dst[e];
        int c = lane;
        float a1 = src_feat[(size_t)si * 64 + c];
        float t1 = bf2f(att_dst[(size_t)di * 128 + c]);
        float t2 = bf2f(att_dst[(size_t)di * 128 + 64 + c]);
        float a2 = efeat[(size_t)e * 64 + c];
        float p = a1 * t1 + a2 * t2;
        #pragma unroll
        for (int off = 32; off > 0; off >>= 1) p += __shfl_xor(p, off, 64);
        float w = expf(p);
        unsafeAtomicAdd(&agg[(size_t)di * 128 + c], w * a1);
        unsafeAtomicAdd(&agg[(size_t)di * 128 + 64 + c], w * a2);
        if (lane == 0) unsafeAtomicAdd(&sums[di], w);
    }
}

// ---------------------------------------------------------------- node post:
// [64 nodes/block] (agg/sum)@Ww (K=128, N=32) + b -> out cols 32..63
__global__ __launch_bounds__(256) void node_post_kernel(
    const float* __restrict__ agg, const float* __restrict__ sums, int N,
    const unsigned short* __restrict__ WT,   // [32][128] bf16 (c-major)
    const float* __restrict__ bias,          // [32]
    float* __restrict__ outp)                // rows stride 64, offset +32
{
    __shared__ unsigned short lA[64 * 128];
    __shared__ unsigned short lW[32 * 128];
    int tid = threadIdx.x;
    int n0 = blockIdx.x * 64;

    const uint4* wsrc = (const uint4*)WT;
    for (int i = tid; i < 32 * 16; i += 256) {
        int r = i >> 4, ch = i & 15;
        *(uint4*)&lW[r * 128 + ((ch ^ (r & 7)) << 3)] = wsrc[i];
    }
    #pragma unroll
    for (int j = 0; j < 8; ++j) {
        int idx4 = j * 256 + tid;
        int r = idx4 >> 5, k = (idx4 & 31) * 4;
        int n = n0 + r;
        float4 v = make_float4(0.f, 0.f, 0.f, 0.f);
        if (n < N) {
            float s = sums[n];
            float sc = (s > 0.f) ? 1.0f / s : 0.f;
            v = *(const float4*)&agg[(size_t)n * 128 + k];
            v.x *= sc; v.y *= sc; v.z *= sc; v.w *= sc;
        }
        uint2 pk;
        pk.x = (unsigned)f2bf(v.x) | ((unsigned)f2bf(v.y) << 16);
        pk.y = (unsigned)f2bf(v.z) | ((unsigned)f2bf(v.w) << 16);
        *(uint2*)&lA[r * 128 + (((k >> 3) ^ (r & 7)) << 3) + (k & 7)] = pk;
    }
    __syncthreads();

    int wv = tid >> 6, lane = tid & 63;
    int r0 = wv * 16;
    int lrow = lane & 15, lkg = lane >> 4;
    int rr = r0 + lrow;

    bf16x8 a[4];
    #pragma unroll
    for (int kk = 0; kk < 4; ++kk) {
        int ch = kk * 4 + lkg;
        a[kk] = *(const bf16x8*)&lA[rr * 128 + ((ch ^ (rr & 7)) << 3)];
    }
    f32x4 acc[2];
    acc[0] = (f32x4){0.f, 0.f, 0.f, 0.f};
    acc[1] = (f32x4){0.f, 0.f, 0.f, 0.f};
    #pragma unroll
    for (int t = 0; t < 2; ++t) {
        int row = t * 16 + lrow;
        #pragma unroll
        for (int kk = 0; kk < 4; ++kk) {
            int ch = kk * 4 + lkg;
            bf16x8 b = *(const bf16x8*)&lW[row * 128 + ((ch ^ (row & 7)) << 3)];
            acc[t] = __builtin_amdgcn_mfma_f32_16x16x32_bf16(a[kk], b, acc[t], 0, 0, 0);
        }
    }
    #pragma unroll
    for (int t = 0; t < 2; ++t) {
        #pragma unroll
        for (int q = 0; q < 4; ++q) {
            int n = n0 + r0 + lkg * 4 + q;
            if (n >= N) continue;
            int c = t * 16 + lrow;
            outp[(size_t)n * 64 + 32 + c] = acc[t][q] + bias[c];
        }
    }
}

// ---------------------------------------------------------------- launch
extern "C" void kernel_launch(void* const* d_in, const int* in_sizes, int n_in,
                              void* d_out, int out_size, void* d_ws, size_t ws_size,
                              hipStream_t stream)
{
    const float* f_feat = (const float*)d_in[0];
    const float* b_feat = (const float*)d_in[1];
    const float* u_feat = (const float*)d_in[2];
    const float* v_feat = (const float*)d_in[3];
    const int* fsrc = (const int*)d_in[4];
    const int* fdst = (const int*)d_in[5];
    const int* bsrc = (const int*)d_in[6];
    const int* bdst = (const int*)d_in[7];
    const float* We  = (const float*)d_in[8];
    const float* be  = (const float*)d_in[9];
    const float* Wul = (const float*)d_in[10];
    const float* bul = (const float*)d_in[11];
    const float* Wvl = (const float*)d_in[12];
    const float* bvl = (const float*)d_in[13];
    const float* Wau = (const float*)d_in[14];
    const float* bau = (const float*)d_in[15];
    const float* Wav = (const float*)d_in[16];
    const float* bav = (const float*)d_in[17];
    const float* Wwu = (const float*)d_in[18];
    const float* bwu = (const float*)d_in[19];
    const float* Wwv = (const float*)d_in[20];
    const float* bwv = (const float*)d_in[21];
    const float* WVu = (const float*)d_in[22];
    const float* bVu = (const float*)d_in[23];
    const float* WVv = (const float*)d_in[24];
    const float* bVv = (const float*)d_in[25];

    int EF = in_sizes[0] / 64;
    int EB = in_sizes[1] / 64;
    int NU = in_sizes[2] / 64;
    int NV = in_sizes[3] / 64;

    float* out = (float*)d_out;
    float* hf = out;
    float* hb = hf + (size_t)EF * 64;
    float* hu = hb + (size_t)EB * 64;
    float* hv = hu + (size_t)NU * 64;

    char* wp = (char*)d_ws;
    auto alloc = [&](size_t bytes) { char* p = wp; wp += (bytes + 255) & ~(size_t)255; return p; };
    unsigned short* he_u  = (unsigned short*)alloc((size_t)NU * 64 * 2);
    unsigned short* he_v  = (unsigned short*)alloc((size_t)NV * 64 * 2);
    unsigned short* att_u = (unsigned short*)alloc((size_t)NU * 128 * 2);
    unsigned short* att_v = (unsigned short*)alloc((size_t)NV * 128 * 2);
    float* agg_u = (float*)alloc((size_t)NU * 128 * 4);
    float* agg_v = (float*)alloc((size_t)NV * 128 * 4);
    float* sum_u = (float*)alloc((size_t)NU * 4);
    float* sum_v = (float*)alloc((size_t)NV * 4);
    unsigned short* WeT  = (unsigned short*)alloc(64 * 64 * 2);
    unsigned short* WuT  = (unsigned short*)alloc(224 * 64 * 2);
    unsigned short* WvT  = (unsigned short*)alloc(224 * 64 * 2);
    unsigned short* WwuT = (unsigned short*)alloc(32 * 128 * 2);
    unsigned short* WwvT = (unsigned short*)alloc(32 * 128 * 2);
    float* bcu = (float*)alloc(224 * 4);
    float* bcv = (float*)alloc(224 * 4);

    prep_kernel<<<64, 256, 0, stream>>>(We, Wul, Wau, WVu, Wvl, Wav, WVv, Wwu, Wwv,
                                        bul, bau, bVu, bvl, bav, bVv,
                                        WeT, WuT, WvT, WwuT, WwvT, bcu, bcv);
    node_pre_kernel<<<(NU + 63) / 64, 256, 0, stream>>>(u_feat, NU, WuT, bcu, he_u, att_u, hu, agg_u, sum_u);
    node_pre_kernel<<<(NV + 63) / 64, 256, 0, stream>>>(v_feat, NV, WvT, bcv, he_v, att_v, hv, agg_v, sum_v);
    edge_kernel<<<(EF + 63) / 64, 256, 0, stream>>>(f_feat, EF, fsrc, fdst, u_feat,
                                                    he_u, he_v, att_v, WeT, be, hf, agg_v, sum_v);
    edge_kernel<<<(EB + 63) / 64, 256, 0, stream>>>(b_feat, EB, bsrc, bdst, v_feat,
                                                    he_v, he_u, att_u, WeT, be, hb, agg_u, sum_u);
    node_post_kernel<<<(NU + 63) / 64, 256, 0, stream>>>(agg_u, sum_u, NU, WwuT, bwu, hu);
    node_post_kernel<<<(NV + 63) / 64, 256, 0, stream>>>(agg_v, sum_v, NV, WwvT, bwv, hv);
}